// Round 1
// baseline (1723.442 us; speedup 1.0000x reference)
//
#include <hip/hip_runtime.h>

// GraphSAGE forward: 2x SAGEConv(mean) + ReLU, then link scorer.
// D = H = 256 throughout.

#define DIM 256

__global__ __launch_bounds__(256) void build_inv(const int* __restrict__ n_id,
                                                 int* __restrict__ inv, int n0) {
    int i = blockIdx.x * blockDim.x + threadIdx.x;
    if (i < n0) inv[n_id[i]] = i;
}

// One 64-lane wave per edge: gather feat[src[e]] (256 f32 as float4/lane),
// atomicAdd into agg[dst[e]]; lane 0 bumps the degree counter.
__global__ __launch_bounds__(256) void edge_agg(const float* __restrict__ feat,
                                                const int* __restrict__ src,
                                                const int* __restrict__ dst,
                                                int E,
                                                float* __restrict__ agg,
                                                float* __restrict__ cnt) {
    int e = blockIdx.x * 4 + (threadIdx.x >> 6);
    if (e >= E) return;
    int lane = threadIdx.x & 63;
    int s = src[e], d = dst[e];
    const float4* xr = (const float4*)(feat + (size_t)s * DIM);
    float4 v = xr[lane];
    float* arow = agg + (size_t)d * DIM + lane * 4;
    atomicAdd(arow + 0, v.x);
    atomicAdd(arow + 1, v.y);
    atomicAdd(arow + 2, v.z);
    atomicAdd(arow + 3, v.w);
    if (lane == 0) atomicAdd(cnt + d, 1.0f);
}

// out[i][j] = relu( (agg[i]/max(cnt[i],1)) @ Wl[:,j] + selfF[i] @ Wr[:,j] + bl[j] )
// M rows, K = N = 256. Block computes a 64x64 tile; 256 threads, 4x4 micro-tile.
__global__ __launch_bounds__(256) void sage_gemm(const float* __restrict__ agg,
                                                 const float* __restrict__ cnt,
                                                 const float* __restrict__ selfF,
                                                 const float* __restrict__ Wl,
                                                 const float* __restrict__ Wr,
                                                 const float* __restrict__ bl,
                                                 float* __restrict__ out, int M) {
    __shared__ float As[64][68];
    __shared__ float Ws[64][68];
    __shared__ float invc[64];
    int row0 = blockIdx.x * 64, col0 = blockIdx.y * 64;
    int t = threadIdx.x;
    if (t < 64) {
        int r = row0 + t;
        invc[t] = (r < M) ? 1.0f / fmaxf(cnt[r], 1.0f) : 0.0f;
    }
    __syncthreads();

    float acc[4][4] = {};
    int tx = t & 15, ty = t >> 4;

    for (int ph = 0; ph < 2; ++ph) {
        const float* __restrict__ A = ph ? selfF : agg;
        const float* __restrict__ W = ph ? Wr : Wl;
        for (int k0 = 0; k0 < 256; k0 += 64) {
            // cooperative load: 64x64 A-tile and 64x64 W-tile, float4 per thread, 4 passes
            int c4 = t & 15;
            int r = t >> 4;
            #pragma unroll
            for (int p = 0; p < 4; ++p, r += 16) {
                int gr = row0 + r;
                float4 v = make_float4(0.f, 0.f, 0.f, 0.f);
                if (gr < M) v = *(const float4*)(A + (size_t)gr * 256 + k0 + c4 * 4);
                float sc = ph ? 1.0f : invc[r];
                As[r][c4 * 4 + 0] = v.x * sc;
                As[r][c4 * 4 + 1] = v.y * sc;
                As[r][c4 * 4 + 2] = v.z * sc;
                As[r][c4 * 4 + 3] = v.w * sc;
                float4 w = *(const float4*)(W + (size_t)(k0 + r) * 256 + col0 + c4 * 4);
                Ws[r][c4 * 4 + 0] = w.x;
                Ws[r][c4 * 4 + 1] = w.y;
                Ws[r][c4 * 4 + 2] = w.z;
                Ws[r][c4 * 4 + 3] = w.w;
            }
            __syncthreads();
            #pragma unroll 16
            for (int k = 0; k < 64; ++k) {
                float a[4], b[4];
                #pragma unroll
                for (int i = 0; i < 4; ++i) a[i] = As[ty * 4 + i][k];
                #pragma unroll
                for (int j = 0; j < 4; ++j) b[j] = Ws[k][tx * 4 + j];
                #pragma unroll
                for (int i = 0; i < 4; ++i)
                    #pragma unroll
                    for (int j = 0; j < 4; ++j) acc[i][j] += a[i] * b[j];
            }
            __syncthreads();
        }
    }

    #pragma unroll
    for (int i = 0; i < 4; ++i) {
        int gr = row0 + ty * 4 + i;
        if (gr >= M) continue;
        #pragma unroll
        for (int j = 0; j < 4; ++j) {
            int gc = col0 + tx * 4 + j;
            float v = acc[i][j] + bl[gc];
            out[(size_t)gr * 256 + gc] = fmaxf(v, 0.0f);
        }
    }
}

// One wave per link: out[l] = h2[inv[link[l,0]]].Wlin[0:256] + h2[inv[link[l,1]]].Wlin[256:512] + blin
__global__ __launch_bounds__(256) void link_pred(const float* __restrict__ h2,
                                                 const int* __restrict__ link,
                                                 const int* __restrict__ inv,
                                                 const float* __restrict__ Wlin,
                                                 const float* __restrict__ blin,
                                                 float* __restrict__ out, int L) {
    int l = blockIdx.x * 4 + (threadIdx.x >> 6);
    if (l >= L) return;
    int lane = threadIdx.x & 63;
    int a = inv[link[2 * l + 0]];
    int b = inv[link[2 * l + 1]];
    float4 ha = ((const float4*)(h2 + (size_t)a * DIM))[lane];
    float4 hb = ((const float4*)(h2 + (size_t)b * DIM))[lane];
    float4 wa = ((const float4*)(Wlin))[lane];
    float4 wb = ((const float4*)(Wlin + DIM))[lane];
    float p = ha.x * wa.x + ha.y * wa.y + ha.z * wa.z + ha.w * wa.w
            + hb.x * wb.x + hb.y * wb.y + hb.z * wb.z + hb.w * wb.w;
    #pragma unroll
    for (int off = 32; off; off >>= 1) p += __shfl_down(p, off, 64);
    if (lane == 0) out[l] = p + blin[0];
}

extern "C" void kernel_launch(void* const* d_in, const int* in_sizes, int n_in,
                              void* d_out, int out_size, void* d_ws, size_t ws_size,
                              hipStream_t stream) {
    const float* x    = (const float*)d_in[0];
    const int*   src1 = (const int*)d_in[1];
    const int*   dst1 = (const int*)d_in[2];
    const int*   src2 = (const int*)d_in[3];
    const int*   dst2 = (const int*)d_in[4];
    const int*   link = (const int*)d_in[7];
    const int*   n_id = (const int*)d_in[8];
    const float* Wl1  = (const float*)d_in[9];
    const float* bl1  = (const float*)d_in[10];
    const float* Wr1  = (const float*)d_in[11];
    const float* Wl2  = (const float*)d_in[12];
    const float* bl2  = (const float*)d_in[13];
    const float* Wr2  = (const float*)d_in[14];
    const float* Wlin = (const float*)d_in[15];
    const float* blin = (const float*)d_in[16];

    const int N0 = in_sizes[0] / DIM;   // 400000
    const int E1 = in_sizes[1];         // 400000
    const int E2 = in_sizes[3];         // 40000
    const int L  = in_sizes[7] / 2;     // 4096
    const int N1 = 40000;               // n1 (device scalar; fixed for this problem)
    const int N2 = 4000;                // n2

    float* ws = (float*)d_ws;
    float* agg1 = ws;  ws += (size_t)N1 * DIM;
    float* cnt1 = ws;  ws += N1;
    float* h1   = ws;  ws += (size_t)N1 * DIM;
    float* agg2 = ws;  ws += (size_t)N2 * DIM;
    float* cnt2 = ws;  ws += N2;
    float* h2   = ws;  ws += (size_t)N2 * DIM;
    int*   inv  = (int*)ws;

    hipMemsetAsync(agg1, 0, (size_t)N1 * DIM * sizeof(float), stream);
    hipMemsetAsync(cnt1, 0, (size_t)N1 * sizeof(float), stream);
    hipMemsetAsync(agg2, 0, (size_t)N2 * DIM * sizeof(float), stream);
    hipMemsetAsync(cnt2, 0, (size_t)N2 * sizeof(float), stream);

    build_inv<<<(N0 + 255) / 256, 256, 0, stream>>>(n_id, inv, N0);
    edge_agg<<<(E1 + 3) / 4, 256, 0, stream>>>(x, src1, dst1, E1, agg1, cnt1);
    sage_gemm<<<dim3((N1 + 63) / 64, 4), 256, 0, stream>>>(agg1, cnt1, x, Wl1, Wr1, bl1, h1, N1);
    edge_agg<<<(E2 + 3) / 4, 256, 0, stream>>>(h1, src2, dst2, E2, agg2, cnt2);
    sage_gemm<<<dim3((N2 + 63) / 64, 4), 256, 0, stream>>>(agg2, cnt2, h1, Wl2, Wr2, bl2, h2, N2);
    link_pred<<<(L + 3) / 4, 256, 0, stream>>>(h2, link, inv, Wlin, blin, (float*)d_out, L);
}

// Round 2
// 399.738 us; speedup vs baseline: 4.3114x; 4.3114x over previous
//
#include <hip/hip_runtime.h>

// GraphSAGE forward: 2x SAGEConv(mean) + ReLU, then link scorer. D = H = 256.
// CSR-based aggregation (no float atomics): hist -> scan -> scatter -> per-node mean.

#define DIM 256

__global__ __launch_bounds__(256) void build_inv(const int* __restrict__ n_id,
                                                 int* __restrict__ inv, int n0) {
    int i = blockIdx.x * blockDim.x + threadIdx.x;
    if (i < n0) inv[n_id[i]] = i;
}

__global__ __launch_bounds__(256) void hist_kernel(const int* __restrict__ dst, int E,
                                                   int* __restrict__ cnt) {
    int i = blockIdx.x * blockDim.x + threadIdx.x;
    if (i < E) atomicAdd(&cnt[dst[i]], 1);
}

// Single-block chunked exclusive scan over n counts (n <= ~64k fine).
// 1024 threads = 16 waves; wave shuffle scan + LDS combine + running carry.
__global__ __launch_bounds__(1024) void scan_csr(const int* __restrict__ cnt, int n,
                                                 int* __restrict__ start,
                                                 int* __restrict__ cursor) {
    __shared__ int wsum[16];
    __shared__ int carry;
    int t = threadIdx.x;
    int lane = t & 63, wid = t >> 6;
    if (t == 0) carry = 0;
    __syncthreads();
    for (int base = 0; base < n; base += 1024) {
        int i = base + t;
        int v = (i < n) ? cnt[i] : 0;
        int x = v;
        #pragma unroll
        for (int off = 1; off < 64; off <<= 1) {
            int y = __shfl_up(x, off, 64);
            if (lane >= off) x += y;
        }
        if (lane == 63) wsum[wid] = x;
        __syncthreads();
        if (wid == 0 && lane < 16) {
            int s = wsum[lane];
            #pragma unroll
            for (int off = 1; off < 16; off <<= 1) {
                int y = __shfl_up(s, off, 64);
                if (lane >= off) s += y;
            }
            wsum[lane] = s;  // inclusive scan of wave sums
        }
        __syncthreads();
        int woff = (wid == 0) ? 0 : wsum[wid - 1];
        int incl = x + woff;
        int excl = incl - v + carry;
        if (i < n) { start[i] = excl; cursor[i] = excl; }
        int chunk_total = wsum[15];
        __syncthreads();            // everyone done reading carry/wsum
        if (t == 0) carry += chunk_total;
        __syncthreads();
    }
}

__global__ __launch_bounds__(256) void scatter_kernel(const int* __restrict__ src,
                                                      const int* __restrict__ dst, int E,
                                                      int* __restrict__ cursor,
                                                      int* __restrict__ eidx) {
    int i = blockIdx.x * blockDim.x + threadIdx.x;
    if (i < E) {
        int d = dst[i];
        int pos = atomicAdd(&cursor[d], 1);
        eidx[pos] = src[i];
    }
}

// One wave per target node: gather neighbor rows (float4/lane), mean, single write.
__global__ __launch_bounds__(256) void csr_mean(const float* __restrict__ feat,
                                                const int* __restrict__ eidx,
                                                const int* __restrict__ start,
                                                const int* __restrict__ cnt, int M,
                                                float* __restrict__ outMean) {
    int node = blockIdx.x * 4 + (threadIdx.x >> 6);
    if (node >= M) return;
    int lane = threadIdx.x & 63;
    int b = start[node], deg = cnt[node];
    float ax = 0.f, ay = 0.f, az = 0.f, aw = 0.f;
    int j = 0;
    for (; j + 2 <= deg; j += 2) {
        int s0 = eidx[b + j];
        int s1 = eidx[b + j + 1];
        float4 v0 = ((const float4*)(feat + (size_t)s0 * DIM))[lane];
        float4 v1 = ((const float4*)(feat + (size_t)s1 * DIM))[lane];
        ax += v0.x + v1.x; ay += v0.y + v1.y;
        az += v0.z + v1.z; aw += v0.w + v1.w;
    }
    if (j < deg) {
        int s0 = eidx[b + j];
        float4 v0 = ((const float4*)(feat + (size_t)s0 * DIM))[lane];
        ax += v0.x; ay += v0.y; az += v0.z; aw += v0.w;
    }
    float sc = deg > 0 ? 1.0f / (float)deg : 0.0f;
    float4 r = make_float4(ax * sc, ay * sc, az * sc, aw * sc);
    ((float4*)(outMean + (size_t)node * DIM))[lane] = r;
}

// out[i][j] = relu( mean[i] @ Wl[:,j] + selfF[i] @ Wr[:,j] + bl[j] )
// M rows, K = N = 256. Block computes a 64x64 tile; 256 threads, 4x4 micro-tile.
__global__ __launch_bounds__(256) void sage_gemm(const float* __restrict__ mean,
                                                 const float* __restrict__ selfF,
                                                 const float* __restrict__ Wl,
                                                 const float* __restrict__ Wr,
                                                 const float* __restrict__ bl,
                                                 float* __restrict__ out, int M) {
    __shared__ float As[64][68];
    __shared__ float Ws[64][68];
    int row0 = blockIdx.x * 64, col0 = blockIdx.y * 64;
    int t = threadIdx.x;

    float acc[4][4] = {};
    int tx = t & 15, ty = t >> 4;

    for (int ph = 0; ph < 2; ++ph) {
        const float* __restrict__ A = ph ? selfF : mean;
        const float* __restrict__ W = ph ? Wr : Wl;
        for (int k0 = 0; k0 < 256; k0 += 64) {
            int c4 = t & 15;
            int r = t >> 4;
            #pragma unroll
            for (int p = 0; p < 4; ++p, r += 16) {
                int gr = row0 + r;
                float4 v = make_float4(0.f, 0.f, 0.f, 0.f);
                if (gr < M) v = *(const float4*)(A + (size_t)gr * 256 + k0 + c4 * 4);
                As[r][c4 * 4 + 0] = v.x;
                As[r][c4 * 4 + 1] = v.y;
                As[r][c4 * 4 + 2] = v.z;
                As[r][c4 * 4 + 3] = v.w;
                float4 w = *(const float4*)(W + (size_t)(k0 + r) * 256 + col0 + c4 * 4);
                Ws[r][c4 * 4 + 0] = w.x;
                Ws[r][c4 * 4 + 1] = w.y;
                Ws[r][c4 * 4 + 2] = w.z;
                Ws[r][c4 * 4 + 3] = w.w;
            }
            __syncthreads();
            #pragma unroll 16
            for (int k = 0; k < 64; ++k) {
                float a[4], b[4];
                #pragma unroll
                for (int i = 0; i < 4; ++i) a[i] = As[ty * 4 + i][k];
                #pragma unroll
                for (int j = 0; j < 4; ++j) b[j] = Ws[k][tx * 4 + j];
                #pragma unroll
                for (int i = 0; i < 4; ++i)
                    #pragma unroll
                    for (int j = 0; j < 4; ++j) acc[i][j] += a[i] * b[j];
            }
            __syncthreads();
        }
    }

    #pragma unroll
    for (int i = 0; i < 4; ++i) {
        int gr = row0 + ty * 4 + i;
        if (gr >= M) continue;
        #pragma unroll
        for (int j = 0; j < 4; ++j) {
            int gc = col0 + tx * 4 + j;
            float v = acc[i][j] + bl[gc];
            out[(size_t)gr * 256 + gc] = fmaxf(v, 0.0f);
        }
    }
}

// One wave per link: out[l] = h2[inv[a]].Wlin[0:256] + h2[inv[b]].Wlin[256:512] + blin
__global__ __launch_bounds__(256) void link_pred(const float* __restrict__ h2,
                                                 const int* __restrict__ link,
                                                 const int* __restrict__ inv,
                                                 const float* __restrict__ Wlin,
                                                 const float* __restrict__ blin,
                                                 float* __restrict__ out, int L) {
    int l = blockIdx.x * 4 + (threadIdx.x >> 6);
    if (l >= L) return;
    int lane = threadIdx.x & 63;
    int a = inv[link[2 * l + 0]];
    int b = inv[link[2 * l + 1]];
    float4 ha = ((const float4*)(h2 + (size_t)a * DIM))[lane];
    float4 hb = ((const float4*)(h2 + (size_t)b * DIM))[lane];
    float4 wa = ((const float4*)(Wlin))[lane];
    float4 wb = ((const float4*)(Wlin + DIM))[lane];
    float p = ha.x * wa.x + ha.y * wa.y + ha.z * wa.z + ha.w * wa.w
            + hb.x * wb.x + hb.y * wb.y + hb.z * wb.z + hb.w * wb.w;
    #pragma unroll
    for (int off = 32; off; off >>= 1) p += __shfl_down(p, off, 64);
    if (lane == 0) out[l] = p + blin[0];
}

extern "C" void kernel_launch(void* const* d_in, const int* in_sizes, int n_in,
                              void* d_out, int out_size, void* d_ws, size_t ws_size,
                              hipStream_t stream) {
    const float* x    = (const float*)d_in[0];
    const int*   src1 = (const int*)d_in[1];
    const int*   dst1 = (const int*)d_in[2];
    const int*   src2 = (const int*)d_in[3];
    const int*   dst2 = (const int*)d_in[4];
    const int*   link = (const int*)d_in[7];
    const int*   n_id = (const int*)d_in[8];
    const float* Wl1  = (const float*)d_in[9];
    const float* bl1  = (const float*)d_in[10];
    const float* Wr1  = (const float*)d_in[11];
    const float* Wl2  = (const float*)d_in[12];
    const float* bl2  = (const float*)d_in[13];
    const float* Wr2  = (const float*)d_in[14];
    const float* Wlin = (const float*)d_in[15];
    const float* blin = (const float*)d_in[16];

    const int N0 = in_sizes[0] / DIM;   // 400000
    const int E1 = in_sizes[1];         // 400000
    const int E2 = in_sizes[3];         // 40000
    const int L  = in_sizes[7] / 2;     // 4096
    const int N1 = 40000;
    const int N2 = 4000;

    char* p = (char*)d_ws;
    auto alloc = [&](size_t bytes) { char* r = p; p += (bytes + 255) & ~(size_t)255; return r; };

    float* mean1 = (float*)alloc((size_t)N1 * DIM * sizeof(float));
    float* h1    = (float*)alloc((size_t)N1 * DIM * sizeof(float));
    float* mean2 = (float*)alloc((size_t)N2 * DIM * sizeof(float));
    float* h2    = (float*)alloc((size_t)N2 * DIM * sizeof(float));
    int*   inv   = (int*)alloc((size_t)N0 * sizeof(int));
    int*   eidx1 = (int*)alloc((size_t)E1 * sizeof(int));
    int*   cnt1  = (int*)alloc((size_t)N1 * sizeof(int));
    int*   st1   = (int*)alloc((size_t)N1 * sizeof(int));
    int*   cur1  = (int*)alloc((size_t)N1 * sizeof(int));
    int*   eidx2 = (int*)alloc((size_t)E2 * sizeof(int));
    int*   cnt2  = (int*)alloc((size_t)N2 * sizeof(int));
    int*   st2   = (int*)alloc((size_t)N2 * sizeof(int));
    int*   cur2  = (int*)alloc((size_t)N2 * sizeof(int));

    hipMemsetAsync(cnt1, 0, (size_t)N1 * sizeof(int), stream);
    hipMemsetAsync(cnt2, 0, (size_t)N2 * sizeof(int), stream);

    build_inv<<<(N0 + 255) / 256, 256, 0, stream>>>(n_id, inv, N0);

    // Layer 1
    hist_kernel<<<(E1 + 255) / 256, 256, 0, stream>>>(dst1, E1, cnt1);
    scan_csr<<<1, 1024, 0, stream>>>(cnt1, N1, st1, cur1);
    scatter_kernel<<<(E1 + 255) / 256, 256, 0, stream>>>(src1, dst1, E1, cur1, eidx1);
    csr_mean<<<(N1 + 3) / 4, 256, 0, stream>>>(x, eidx1, st1, cnt1, N1, mean1);
    sage_gemm<<<dim3((N1 + 63) / 64, 4), 256, 0, stream>>>(mean1, x, Wl1, Wr1, bl1, h1, N1);

    // Layer 2
    hist_kernel<<<(E2 + 255) / 256, 256, 0, stream>>>(dst2, E2, cnt2);
    scan_csr<<<1, 1024, 0, stream>>>(cnt2, N2, st2, cur2);
    scatter_kernel<<<(E2 + 255) / 256, 256, 0, stream>>>(src2, dst2, E2, cur2, eidx2);
    csr_mean<<<(N2 + 3) / 4, 256, 0, stream>>>(h1, eidx2, st2, cnt2, N2, mean2);
    sage_gemm<<<dim3((N2 + 63) / 64, 4), 256, 0, stream>>>(mean2, h1, Wl2, Wr2, bl2, h2, N2);

    link_pred<<<(L + 3) / 4, 256, 0, stream>>>(h2, link, inv, Wlin, blin, (float*)d_out, L);
}

// Round 3
// 243.515 us; speedup vs baseline: 7.0773x; 1.6415x over previous
//
#include <hip/hip_runtime.h>

// GraphSAGE forward: 2x SAGEConv(mean) + ReLU, then link scorer. D = H = 256.
// CSR aggregation (no float atomics) + bf16 MFMA GEMMs with packed weights.

#define DIM 256
typedef __attribute__((ext_vector_type(8))) short short8v;
typedef __attribute__((ext_vector_type(4))) float f32x4;

__device__ inline unsigned short f2b(float f) {
    unsigned u = __builtin_bit_cast(unsigned, f);
    unsigned r = 0x7FFFu + ((u >> 16) & 1u);
    return (unsigned short)((u + r) >> 16);
}
__device__ inline float b2f(unsigned short h) {
    unsigned u = ((unsigned)h) << 16;
    return __builtin_bit_cast(float, u);
}

// Fused prep: inv scatter, zero both count arrays, cast x[:n1] rows to bf16.
__global__ __launch_bounds__(256) void prep(const int* __restrict__ n_id,
                                            int* __restrict__ inv, int n0,
                                            int* __restrict__ c1, int n1_,
                                            int* __restrict__ c2, int n2_,
                                            const float* __restrict__ x,
                                            unsigned short* __restrict__ xb, int castChunks) {
    int i = blockIdx.x * blockDim.x + threadIdx.x;
    if (i < n0) inv[n_id[i]] = i;
    if (i < n1_) c1[i] = 0;
    if (i < n2_) c2[i] = 0;
    if (i < castChunks) {  // 8 elems per chunk
        const float4* src = (const float4*)(x + (size_t)i * 8);
        float4 a = src[0], b = src[1];
        short8v v;
        v[0] = f2b(a.x); v[1] = f2b(a.y); v[2] = f2b(a.z); v[3] = f2b(a.w);
        v[4] = f2b(b.x); v[5] = f2b(b.y); v[6] = f2b(b.z); v[7] = f2b(b.w);
        *(short8v*)(xb + (size_t)i * 8) = v;
    }
}

// Pack 256x256 f32 row-major weight into bf16 MFMA B-fragment order:
// P[((nt*8+kt)*64+lane)*8+j] = bf16(W[kt*32 + 8*(lane>>4)+j][nt*16 + (lane&15)])
__global__ __launch_bounds__(64) void pack_w4(const float* __restrict__ W0, const float* __restrict__ W1,
                                              const float* __restrict__ W2, const float* __restrict__ W3,
                                              unsigned short* __restrict__ P0, unsigned short* __restrict__ P1,
                                              unsigned short* __restrict__ P2, unsigned short* __restrict__ P3) {
    const float* W; unsigned short* P;
    switch (blockIdx.z) {
        case 0: W = W0; P = P0; break;
        case 1: W = W1; P = P1; break;
        case 2: W = W2; P = P2; break;
        default: W = W3; P = P3; break;
    }
    int nt = blockIdx.x, kt = blockIdx.y, lane = threadIdx.x;
    int r = kt * 32 + ((lane >> 4) * 8);
    int c = nt * 16 + (lane & 15);
    short8v v;
    #pragma unroll
    for (int j = 0; j < 8; ++j) v[j] = f2b(W[(size_t)(r + j) * 256 + c]);
    *(short8v*)(P + ((size_t)(nt * 8 + kt) * 64 + lane) * 8) = v;
}

__global__ __launch_bounds__(256) void hist_both(const int* __restrict__ dst1, int E1,
                                                 const int* __restrict__ dst2, int E2,
                                                 int* __restrict__ c1, int* __restrict__ c2) {
    int i = blockIdx.x * blockDim.x + threadIdx.x;
    if (i < E1) atomicAdd(&c1[dst1[i]], 1);
    else if (i < E1 + E2) atomicAdd(&c2[dst2[i - E1]], 1);
}

// blockIdx.x selects which count array to scan (2 blocks).
__global__ __launch_bounds__(1024) void scan_both(const int* __restrict__ cnt1, int n1_,
                                                  int* __restrict__ st1, int* __restrict__ cur1,
                                                  const int* __restrict__ cnt2, int n2_,
                                                  int* __restrict__ st2, int* __restrict__ cur2) {
    const int* cnt = blockIdx.x ? cnt2 : cnt1;
    int n = blockIdx.x ? n2_ : n1_;
    int* start = blockIdx.x ? st2 : st1;
    int* cursor = blockIdx.x ? cur2 : cur1;
    __shared__ int wsum[16];
    __shared__ int carry;
    int t = threadIdx.x;
    int lane = t & 63, wid = t >> 6;
    if (t == 0) carry = 0;
    __syncthreads();
    for (int base = 0; base < n; base += 1024) {
        int i = base + t;
        int v = (i < n) ? cnt[i] : 0;
        int x = v;
        #pragma unroll
        for (int off = 1; off < 64; off <<= 1) {
            int y = __shfl_up(x, off, 64);
            if (lane >= off) x += y;
        }
        if (lane == 63) wsum[wid] = x;
        __syncthreads();
        if (wid == 0 && lane < 16) {
            int s = wsum[lane];
            #pragma unroll
            for (int off = 1; off < 16; off <<= 1) {
                int y = __shfl_up(s, off, 64);
                if (lane >= off) s += y;
            }
            wsum[lane] = s;
        }
        __syncthreads();
        int woff = (wid == 0) ? 0 : wsum[wid - 1];
        int excl = x + woff - v + carry;
        if (i < n) { start[i] = excl; cursor[i] = excl; }
        int chunk_total = wsum[15];
        __syncthreads();
        if (t == 0) carry += chunk_total;
        __syncthreads();
    }
}

__global__ __launch_bounds__(256) void scatter_both(const int* __restrict__ src1,
                                                    const int* __restrict__ dst1, int E1,
                                                    const int* __restrict__ src2,
                                                    const int* __restrict__ dst2, int E2,
                                                    int* __restrict__ cur1, int* __restrict__ eidx1,
                                                    int* __restrict__ cur2, int* __restrict__ eidx2) {
    int i = blockIdx.x * blockDim.x + threadIdx.x;
    if (i < E1) {
        int pos = atomicAdd(&cur1[dst1[i]], 1);
        eidx1[pos] = src1[i];
    } else if (i < E1 + E2) {
        int j = i - E1;
        int pos = atomicAdd(&cur2[dst2[j]], 1);
        eidx2[pos] = src2[j];
    }
}

// One wave per node: gather fp32 rows, mean, write bf16 row.
__global__ __launch_bounds__(256) void csr_mean_f32b16(const float* __restrict__ feat,
                                                       const int* __restrict__ eidx,
                                                       const int* __restrict__ start,
                                                       const int* __restrict__ cnt, int M,
                                                       unsigned short* __restrict__ outMean) {
    int node = blockIdx.x * 4 + (threadIdx.x >> 6);
    if (node >= M) return;
    int lane = threadIdx.x & 63;
    int b = start[node], deg = cnt[node];
    float ax = 0.f, ay = 0.f, az = 0.f, aw = 0.f;
    int j = 0;
    for (; j + 4 <= deg; j += 4) {
        int s0 = eidx[b + j], s1 = eidx[b + j + 1], s2 = eidx[b + j + 2], s3 = eidx[b + j + 3];
        float4 v0 = ((const float4*)(feat + (size_t)s0 * DIM))[lane];
        float4 v1 = ((const float4*)(feat + (size_t)s1 * DIM))[lane];
        float4 v2 = ((const float4*)(feat + (size_t)s2 * DIM))[lane];
        float4 v3 = ((const float4*)(feat + (size_t)s3 * DIM))[lane];
        ax += (v0.x + v1.x) + (v2.x + v3.x);
        ay += (v0.y + v1.y) + (v2.y + v3.y);
        az += (v0.z + v1.z) + (v2.z + v3.z);
        aw += (v0.w + v1.w) + (v2.w + v3.w);
    }
    for (; j < deg; ++j) {
        int s0 = eidx[b + j];
        float4 v0 = ((const float4*)(feat + (size_t)s0 * DIM))[lane];
        ax += v0.x; ay += v0.y; az += v0.z; aw += v0.w;
    }
    float sc = deg > 0 ? 1.0f / (float)deg : 0.0f;
    ushort4 r;
    r.x = f2b(ax * sc); r.y = f2b(ay * sc); r.z = f2b(az * sc); r.w = f2b(aw * sc);
    ((ushort4*)(outMean + (size_t)node * DIM))[lane] = r;
}

// One wave per node: gather bf16 rows (8B/lane), mean, write bf16 row.
__global__ __launch_bounds__(256) void csr_mean_b16b16(const unsigned short* __restrict__ feat,
                                                       const int* __restrict__ eidx,
                                                       const int* __restrict__ start,
                                                       const int* __restrict__ cnt, int M,
                                                       unsigned short* __restrict__ outMean) {
    int node = blockIdx.x * 4 + (threadIdx.x >> 6);
    if (node >= M) return;
    int lane = threadIdx.x & 63;
    int b = start[node], deg = cnt[node];
    float ax = 0.f, ay = 0.f, az = 0.f, aw = 0.f;
    int j = 0;
    for (; j + 2 <= deg; j += 2) {
        int s0 = eidx[b + j], s1 = eidx[b + j + 1];
        ushort4 v0 = ((const ushort4*)(feat + (size_t)s0 * DIM))[lane];
        ushort4 v1 = ((const ushort4*)(feat + (size_t)s1 * DIM))[lane];
        ax += b2f(v0.x) + b2f(v1.x); ay += b2f(v0.y) + b2f(v1.y);
        az += b2f(v0.z) + b2f(v1.z); aw += b2f(v0.w) + b2f(v1.w);
    }
    if (j < deg) {
        int s0 = eidx[b + j];
        ushort4 v0 = ((const ushort4*)(feat + (size_t)s0 * DIM))[lane];
        ax += b2f(v0.x); ay += b2f(v0.y); az += b2f(v0.z); aw += b2f(v0.w);
    }
    float sc = deg > 0 ? 1.0f / (float)deg : 0.0f;
    ushort4 r;
    r.x = f2b(ax * sc); r.y = f2b(ay * sc); r.z = f2b(az * sc); r.w = f2b(aw * sc);
    ((ushort4*)(outMean + (size_t)node * DIM))[lane] = r;
}

// out = relu(mean @ Wl + self @ Wr + bl). A direct-from-global, B from packed
// fragments. Block 64x64 tile, 4 waves 2x2, each wave 32x32 (2x2 MFMA subtiles).
template <int OUT_BF16>
__global__ __launch_bounds__(256) void gemm_mfma(const unsigned short* __restrict__ meanb,
                                                 const unsigned short* __restrict__ selfb,
                                                 const unsigned short* __restrict__ PWl,
                                                 const unsigned short* __restrict__ PWr,
                                                 const float* __restrict__ bl,
                                                 void* __restrict__ out, int M) {
    int t = threadIdx.x;
    int lane = t & 63, wid = t >> 6;
    int wr = wid >> 1, wc = wid & 1;
    int row0 = blockIdx.x * 64 + wr * 32;
    int col0 = blockIdx.y * 64 + wc * 32;

    int arow0 = row0 + (lane & 15);
    int arow1 = arow0 + 16;
    if (arow0 >= M) arow0 = M - 1;  // clamped loads; stores guarded below
    if (arow1 >= M) arow1 = M - 1;
    int koff = (lane >> 4) * 8;
    int nt0 = col0 >> 4;

    f32x4 acc[2][2] = {};
    #pragma unroll
    for (int half = 0; half < 2; ++half) {
        const unsigned short* A = half ? selfb : meanb;
        const unsigned short* PW = half ? PWr : PWl;
        const unsigned short* a0p = A + (size_t)arow0 * 256 + koff;
        const unsigned short* a1p = A + (size_t)arow1 * 256 + koff;
        const unsigned short* b0p = PW + (size_t)nt0 * 4096 + lane * 8;
        const unsigned short* b1p = b0p + 4096;
        #pragma unroll
        for (int kt = 0; kt < 8; ++kt) {
            short8v a0 = *(const short8v*)(a0p + kt * 32);
            short8v a1 = *(const short8v*)(a1p + kt * 32);
            short8v b0 = *(const short8v*)(b0p + kt * 512);
            short8v b1 = *(const short8v*)(b1p + kt * 512);
            acc[0][0] = __builtin_amdgcn_mfma_f32_16x16x32_bf16(a0, b0, acc[0][0], 0, 0, 0);
            acc[0][1] = __builtin_amdgcn_mfma_f32_16x16x32_bf16(a0, b1, acc[0][1], 0, 0, 0);
            acc[1][0] = __builtin_amdgcn_mfma_f32_16x16x32_bf16(a1, b0, acc[1][0], 0, 0, 0);
            acc[1][1] = __builtin_amdgcn_mfma_f32_16x16x32_bf16(a1, b1, acc[1][1], 0, 0, 0);
        }
    }

    int rbase = (lane >> 4) * 4;
    #pragma unroll
    for (int i = 0; i < 2; ++i) {
        #pragma unroll
        for (int j = 0; j < 2; ++j) {
            int col = col0 + j * 16 + (lane & 15);
            float bias = bl[col];
            #pragma unroll
            for (int r = 0; r < 4; ++r) {
                int row = row0 + i * 16 + rbase + r;
                if (row >= M) continue;
                float v = fmaxf(acc[i][j][r] + bias, 0.0f);
                if (OUT_BF16)
                    ((unsigned short*)out)[(size_t)row * 256 + col] = f2b(v);
                else
                    ((float*)out)[(size_t)row * 256 + col] = v;
            }
        }
    }
}

// One wave per link: out[l] = h2[inv[a]].Wlin[0:256] + h2[inv[b]].Wlin[256:512] + blin
__global__ __launch_bounds__(256) void link_pred(const float* __restrict__ h2,
                                                 const int* __restrict__ link,
                                                 const int* __restrict__ inv,
                                                 const float* __restrict__ Wlin,
                                                 const float* __restrict__ blin,
                                                 float* __restrict__ out, int L) {
    int l = blockIdx.x * 4 + (threadIdx.x >> 6);
    if (l >= L) return;
    int lane = threadIdx.x & 63;
    int a = inv[link[2 * l + 0]];
    int b = inv[link[2 * l + 1]];
    float4 ha = ((const float4*)(h2 + (size_t)a * DIM))[lane];
    float4 hb = ((const float4*)(h2 + (size_t)b * DIM))[lane];
    float4 wa = ((const float4*)(Wlin))[lane];
    float4 wb = ((const float4*)(Wlin + DIM))[lane];
    float p = ha.x * wa.x + ha.y * wa.y + ha.z * wa.z + ha.w * wa.w
            + hb.x * wb.x + hb.y * wb.y + hb.z * wb.z + hb.w * wb.w;
    #pragma unroll
    for (int off = 32; off; off >>= 1) p += __shfl_down(p, off, 64);
    if (lane == 0) out[l] = p + blin[0];
}

extern "C" void kernel_launch(void* const* d_in, const int* in_sizes, int n_in,
                              void* d_out, int out_size, void* d_ws, size_t ws_size,
                              hipStream_t stream) {
    const float* x    = (const float*)d_in[0];
    const int*   src1 = (const int*)d_in[1];
    const int*   dst1 = (const int*)d_in[2];
    const int*   src2 = (const int*)d_in[3];
    const int*   dst2 = (const int*)d_in[4];
    const int*   link = (const int*)d_in[7];
    const int*   n_id = (const int*)d_in[8];
    const float* Wl1  = (const float*)d_in[9];
    const float* bl1  = (const float*)d_in[10];
    const float* Wr1  = (const float*)d_in[11];
    const float* Wl2  = (const float*)d_in[12];
    const float* bl2  = (const float*)d_in[13];
    const float* Wr2  = (const float*)d_in[14];
    const float* Wlin = (const float*)d_in[15];
    const float* blin = (const float*)d_in[16];

    const int N0 = in_sizes[0] / DIM;   // 400000
    const int E1 = in_sizes[1];         // 400000
    const int E2 = in_sizes[3];         // 40000
    const int L  = in_sizes[7] / 2;     // 4096
    const int N1 = 40000;
    const int N2 = 4000;

    char* p = (char*)d_ws;
    auto alloc = [&](size_t bytes) { char* r = p; p += (bytes + 255) & ~(size_t)255; return r; };

    unsigned short* meanb1 = (unsigned short*)alloc((size_t)N1 * DIM * 2);
    unsigned short* selfb1 = (unsigned short*)alloc((size_t)N1 * DIM * 2);
    unsigned short* h1b    = (unsigned short*)alloc((size_t)N1 * DIM * 2);
    unsigned short* meanb2 = (unsigned short*)alloc((size_t)N2 * DIM * 2);
    float*          h2     = (float*)alloc((size_t)N2 * DIM * 4);
    unsigned short* PWl1   = (unsigned short*)alloc(256 * 256 * 2);
    unsigned short* PWr1   = (unsigned short*)alloc(256 * 256 * 2);
    unsigned short* PWl2   = (unsigned short*)alloc(256 * 256 * 2);
    unsigned short* PWr2   = (unsigned short*)alloc(256 * 256 * 2);
    int* inv   = (int*)alloc((size_t)N0 * 4);
    int* eidx1 = (int*)alloc((size_t)E1 * 4);
    int* cnt1  = (int*)alloc((size_t)N1 * 4);
    int* st1   = (int*)alloc((size_t)N1 * 4);
    int* cur1  = (int*)alloc((size_t)N1 * 4);
    int* eidx2 = (int*)alloc((size_t)E2 * 4);
    int* cnt2  = (int*)alloc((size_t)N2 * 4);
    int* st2   = (int*)alloc((size_t)N2 * 4);
    int* cur2  = (int*)alloc((size_t)N2 * 4);

    const int castChunks = N1 * DIM / 8;  // bf16 cast of x[:N1]
    int prepThreads = max(N0, castChunks);
    prep<<<(prepThreads + 255) / 256, 256, 0, stream>>>(n_id, inv, N0, cnt1, N1, cnt2, N2,
                                                        x, selfb1, castChunks);
    pack_w4<<<dim3(16, 8, 4), 64, 0, stream>>>(Wl1, Wr1, Wl2, Wr2, PWl1, PWr1, PWl2, PWr2);
    hist_both<<<(E1 + E2 + 255) / 256, 256, 0, stream>>>(dst1, E1, dst2, E2, cnt1, cnt2);
    scan_both<<<2, 1024, 0, stream>>>(cnt1, N1, st1, cur1, cnt2, N2, st2, cur2);
    scatter_both<<<(E1 + E2 + 255) / 256, 256, 0, stream>>>(src1, dst1, E1, src2, dst2, E2,
                                                            cur1, eidx1, cur2, eidx2);

    csr_mean_f32b16<<<(N1 + 3) / 4, 256, 0, stream>>>(x, eidx1, st1, cnt1, N1, meanb1);
    gemm_mfma<1><<<dim3(N1 / 64, 4), 256, 0, stream>>>(meanb1, selfb1, PWl1, PWr1, bl1, h1b, N1);

    csr_mean_b16b16<<<(N2 + 3) / 4, 256, 0, stream>>>(h1b, eidx2, st2, cnt2, N2, meanb2);
    gemm_mfma<0><<<dim3((N2 + 63) / 64, 4), 256, 0, stream>>>(meanb2, h1b, PWl2, PWr2, bl2, h2, N2);

    link_pred<<<(L + 3) / 4, 256, 0, stream>>>(h2, link, inv, Wlin, blin, (float*)d_out, L);
}